// Round 1
// baseline (213.423 us; speedup 1.0000x reference)
//
#include <hip/hip_runtime.h>
#include <math.h>

#define IMG_W 2048
#define IMG_H 2048
#define BATCH 8
#define MAX_PEAKS ((BATCH * IMG_H * IMG_W) / 8)   // 4194304
#define NWORDS (BATCH * IMG_H * IMG_W / 32)       // 1048576
#define ROWSW 32                                  // rows per wave
#define NFILL 2048                                // tail-fill blocks

// ---------------------------------------------------------------------------
// K1: register-ring NMS mask with DISTANCE-3 SOFTWARE PIPELINE.
// Previous version loaded a row and consumed it in the SAME iteration
// (vmcnt(0) every row -> full HBM latency exposed, only 4 waves/SIMD TLP).
// Now: iteration U issues the load of row r0+U+5 into slot (U+7)&7, which is
// first consumed 3 iterations later -> 3 row-iterations (~500+ cycles) of
// own-wave compute hide the miss, 6 loads in flight.
// Interior waves (125/128) take a fast path: no row clamp, no validity
// selects, pure pointer stepping. Edge halo is loaded as float2 directly at
// the needed columns (no float4 + leftHalf select).
// mask bit = (s > 0) && (s >= 5x5 window max); -inf outside the image.
// ---------------------------------------------------------------------------

#define NMS_COMPUTE(uu)                                                       \
  {                                                                           \
    const float4 w0 = ring[(uu) & 7];                                         \
    const float4 w1 = ring[((uu) + 1) & 7];                                   \
    const float4 mid = ring[((uu) + 2) & 7];                                  \
    const float4 w3 = ring[((uu) + 3) & 7];                                   \
    const float4 w4 = ring[((uu) + 4) & 7];                                   \
    float vmx = fmaxf(fmaxf(fmaxf(w0.x, w1.x), fmaxf(mid.x, w3.x)), w4.x);    \
    float vmy = fmaxf(fmaxf(fmaxf(w0.y, w1.y), fmaxf(mid.y, w3.y)), w4.y);    \
    float vmz = fmaxf(fmaxf(fmaxf(w0.z, w1.z), fmaxf(mid.z, w3.z)), w4.z);    \
    float vmw = fmaxf(fmaxf(fmaxf(w0.w, w1.w), fmaxf(mid.w, w3.w)), w4.w);    \
    const float2 e0 = ringE[(uu) & 7];                                        \
    const float2 e1 = ringE[((uu) + 1) & 7];                                  \
    const float2 e2 = ringE[((uu) + 2) & 7];                                  \
    const float2 e3 = ringE[((uu) + 3) & 7];                                  \
    const float2 e4 = ringE[((uu) + 4) & 7];                                  \
    float vex = fmaxf(fmaxf(fmaxf(e0.x, e1.x), fmaxf(e2.x, e3.x)), e4.x);     \
    float vey = fmaxf(fmaxf(fmaxf(e0.y, e1.y), fmaxf(e2.y, e3.y)), e4.y);     \
    float Av = __shfl_up(vmz, 1);                                             \
    float Bv = __shfl_up(vmw, 1);                                             \
    float Cv = __shfl_down(vmx, 1);                                           \
    float Dv = __shfl_down(vmy, 1);                                           \
    if (isL) { Av = vex; Bv = vey; }                                          \
    if (isR) { Cv = vex; Dv = vey; }                                          \
    float t12 = fmaxf(vmy, vmz);                                              \
    float m02 = fmaxf(vmx, t12);                                              \
    float m03 = fmaxf(m02, vmw);                                              \
    float m13 = fmaxf(t12, vmw);                                              \
    float h0 = fmaxf(fmaxf(Av, Bv), m02);                                     \
    float h1 = fmaxf(Bv, m03);                                                \
    float h2 = fmaxf(m03, Cv);                                                \
    float h3 = fmaxf(m13, fmaxf(Cv, Dv));                                     \
    unsigned nib = 0;                                                         \
    nib |= (mid.x > 0.0f && mid.x >= h0) ? 1u : 0u;                           \
    nib |= (mid.y > 0.0f && mid.y >= h1) ? 2u : 0u;                           \
    nib |= (mid.z > 0.0f && mid.z >= h2) ? 4u : 0u;                           \
    nib |= (mid.w > 0.0f && mid.w >= h3) ? 8u : 0u;                           \
    unsigned wd = nib << shamt;                                               \
    wd |= __shfl_xor(wd, 1);                                                  \
    wd |= __shfl_xor(wd, 2);                                                  \
    wd |= __shfl_xor(wd, 4);                                                  \
    if ((lane & 7) == 0) {                                                    \
      words[wIdx] = wd;                                                       \
      cnt += __popc(wd);                                                      \
    }                                                                         \
    wIdx += IMG_W / 32;                                                       \
  }

// fast-path prefetch: unclamped pointer stepping, distance 3 -> slot (uu+7)&7
#define PF_FAST(uu)                                                           \
  {                                                                           \
    ring[((uu) + 7) & 7] = *(const float4*)p;                                 \
    const float2 _e = *(const float2*)pe;                                     \
    float2 _ne;                                                               \
    _ne.x = evalid ? _e.x : NEG;                                              \
    _ne.y = evalid ? _e.y : NEG;                                              \
    ringE[((uu) + 7) & 7] = _ne;                                              \
    p += IMG_W;                                                               \
    pe += IMG_W;                                                              \
  }

// slow-path prefetch: row clamp + validity selects, same slot math
#define PF_SLOW(uu, gr)                                                       \
  {                                                                           \
    const int _rc = (gr) < 0 ? 0 : ((gr) > IMG_H - 1 ? IMG_H - 1 : (gr));     \
    const size_t _off = (size_t)_rc * IMG_W;                                  \
    const float4 _v = *(const float4*)(colp + _off);                          \
    const float2 _e = *(const float2*)(ecolp + _off);                         \
    const bool _rv = ((unsigned)(gr) < (unsigned)IMG_H);                      \
    const bool _ok = _rv && evalid;                                           \
    float4 _nv;                                                               \
    float2 _ne;                                                               \
    _nv.x = _rv ? _v.x : NEG;                                                 \
    _nv.y = _rv ? _v.y : NEG;                                                 \
    _nv.z = _rv ? _v.z : NEG;                                                 \
    _nv.w = _rv ? _v.w : NEG;                                                 \
    _ne.x = _ok ? _e.x : NEG;                                                 \
    _ne.y = _ok ? _e.y : NEG;                                                 \
    ring[((uu) + 7) & 7] = _nv;                                               \
    ringE[((uu) + 7) & 7] = _ne;                                              \
  }

#define FLUSH(k)                                                              \
  {                                                                           \
    unsigned s = cnt;                                                         \
    s += __shfl_xor(s, 1);                                                    \
    s += __shfl_xor(s, 2);                                                    \
    s += __shfl_xor(s, 4);                                                    \
    s += __shfl_xor(s, 8);                                                    \
    s += __shfl_xor(s, 16);                                                   \
    s += __shfl_xor(s, 32);                                                   \
    if (lane == 0) bsum2[(cb0 + (k)) * 8 + strip] = s;                        \
    cnt = 0;                                                                  \
  }

__global__ __launch_bounds__(256, 4) void nms_mask(const float* __restrict__ scores,
                                                   unsigned* __restrict__ words,
                                                   unsigned* __restrict__ bsum2) {
    const int t = threadIdx.x;
    const int lane = t & 63;
    const int wv = t >> 6;
    const int b = blockIdx.x;         // 0..1023
    const int img = b >> 7;           // 8 images x 128 blocks
    const int rem = b & 127;
    const int strip = rem >> 4;       // 8 column strips of 256
    const int chunk = rem & 15;       // 16 row chunks of 128
    const int r0 = chunk * 128 + wv * ROWSW;
    const int c0 = strip * 256;
    const int cl = c0 + lane * 4;
    const size_t imgBase = (size_t)img * ((size_t)IMG_H * IMG_W);
    const float NEG = -INFINITY;

    const float* colp = scores + imgBase + cl;
    const bool leftHalf = (lane < 32);
    const bool isL = (lane == 0), isR = (lane == 63);
    // float2 edge halo: left half needs cols (c0-2,c0-1); right half (c0+256,c0+257)
    const int ecol2 = leftHalf ? (c0 - 2) : (c0 + 256);
    const bool evalid = ((unsigned)ecol2 < (unsigned)IMG_W);
    const int ecol2C = evalid ? ecol2 : c0;     // clamped valid address
    const float* ecolp = scores + imgBase + ecol2C;

    float4 ring[8];
    float2 ringE[8];

    unsigned cnt = 0;
    const int shamt = (lane & 7) * 4;
    size_t wIdx = (size_t)(img * IMG_H + r0) * (IMG_W / 32) + strip * 8 + (lane >> 3);
    const int cb0 = (img * IMG_H + r0) >> 4;   // compact-block (16-row) index

    // interior: warm-up rows r0-2..r0+4 and steady rows up to r0+33 all valid
    const bool rowsInterior = (r0 >= 2) && (r0 + 33 <= IMG_H - 1);

    if (rowsInterior) {
        const float* p = colp + (size_t)(r0 - 2) * IMG_W;
        const float* pe = ecolp + (size_t)(r0 - 2) * IMG_W;
        // warm-up: rows r0-2..r0+4 -> slots 0..6
#pragma unroll
        for (int m = 0; m < 7; ++m) {
            ring[m] = *(const float4*)p;
            const float2 _e = *(const float2*)pe;
            ringE[m].x = evalid ? _e.x : NEG;
            ringE[m].y = evalid ? _e.y : NEG;
            p += IMG_W;
            pe += IMG_W;
        }
        // p now at row r0+5: the U=0 prefetch (consumed at U=3)
#pragma unroll 1
        for (int i8 = 0; i8 < 2; ++i8) {   // U = 0..15
#pragma unroll
            for (int uu = 0; uu < 8; ++uu) {
                PF_FAST(uu);
                NMS_COMPUTE(uu);
            }
        }
        FLUSH(0);
#pragma unroll
        for (int uu = 0; uu < 8; ++uu) {   // U = 16..23
            PF_FAST(uu);
            NMS_COMPUTE(uu);
        }
#pragma unroll
        for (int uu = 0; uu < 5; ++uu) {   // U = 24..28 (last useful loads: r0+33)
            PF_FAST(uu);
            NMS_COMPUTE(uu);
        }
#pragma unroll
        for (int uu = 5; uu < 8; ++uu) {   // U = 29..31, no prefetch
            NMS_COMPUTE(uu);
        }
        FLUSH(1);
    } else {
        // warm-up: rows r0-2..r0+4 -> slots 0..6 (clamped + -inf selects)
#pragma unroll
        for (int m = 0; m < 7; ++m) {
            PF_SLOW(m - 7, r0 - 2 + m);
        }
#pragma unroll 1
        for (int i8 = 0; i8 < 4; ++i8) {
#pragma unroll
            for (int uu = 0; uu < 8; ++uu) {
                const int U = i8 * 8 + uu;
                PF_SLOW(uu, r0 + U + 5);   // rows past r0+33 are clamped dups, unused
                NMS_COMPUTE(uu);
            }
            if (i8 & 1) FLUSH(i8 >> 1);
        }
    }
}

// ---------------------------------------------------------------------------
// K2: scan. Reduce 8 strip-sums per 16-row chunk (8192 slots -> 1024 cbs),
// exclusive scan, base[1024] = total. One 256-thread block.
// ---------------------------------------------------------------------------
__global__ __launch_bounds__(256) void nms_scan(const unsigned* __restrict__ bsum2,
                                                unsigned* __restrict__ base) {
    __shared__ unsigned wtot[4];
    const int t = threadIdx.x;
    const int lane = t & 63, wid = t >> 6;
    const uint4* p = (const uint4*)(bsum2 + t * 32);   // 4 cbs x 8 slots
    unsigned c[4];
#pragma unroll
    for (int i = 0; i < 4; ++i) {
        uint4 a = p[2 * i], bq = p[2 * i + 1];
        c[i] = a.x + a.y + a.z + a.w + bq.x + bq.y + bq.z + bq.w;
    }
    unsigned s0 = c[0], s1 = s0 + c[1], s2 = s1 + c[2], ts = s2 + c[3];
    unsigned sc = ts;
#pragma unroll
    for (int d = 1; d < 64; d <<= 1) {
        unsigned o = __shfl_up(sc, d);
        if (lane >= d) sc += o;
    }
    if (lane == 63) wtot[wid] = sc;
    __syncthreads();
    unsigned wpre = 0;
#pragma unroll
    for (int k = 0; k < 4; ++k) wpre += (k < wid) ? wtot[k] : 0u;
    unsigned excl = wpre + sc - ts;
    ((uint4*)base)[t] = make_uint4(excl, excl + s0, excl + s1, excl + s2);
    if (t == 255) base[1024] = wpre + sc;
}

// ---------------------------------------------------------------------------
// K3: ordered compaction (blocks 0..1023) + -1 tail fill (blocks 1024..),
// tail fill now int4-vectorized on the 16B-aligned body.
// ---------------------------------------------------------------------------
__global__ __launch_bounds__(256) void nms_compact(const unsigned* __restrict__ words,
                                                   const unsigned* __restrict__ base,
                                                   int* __restrict__ out) {
    const int t = threadIdx.x;
    const int b = blockIdx.x;
    if (b < 1024) {
        __shared__ unsigned wq[4];
        const int lane = t & 63, wid = t >> 6;
        uint4 q = ((const uint4*)(words + b * 1024))[t];
        unsigned wv[4] = {q.x, q.y, q.z, q.w};
        unsigned tsum = __popc(wv[0]) + __popc(wv[1]) + __popc(wv[2]) + __popc(wv[3]);
        unsigned sc = tsum;
#pragma unroll
        for (int d = 1; d < 64; d <<= 1) {
            unsigned o = __shfl_up(sc, d);
            if (lane >= d) sc += o;
        }
        if (lane == 63) wq[wid] = sc;
        __syncthreads();
        unsigned wpre = 0;
#pragma unroll
        for (int k = 0; k < 4; ++k) wpre += (k < wid) ? wq[k] : 0u;
        unsigned off = base[b] + wpre + sc - tsum;

        const unsigned gword0 = (unsigned)b * 1024u + (unsigned)t * 4u;
#pragma unroll
        for (int wi = 0; wi < 4; ++wi) {
            unsigned m = wv[wi];
            unsigned pbase = (gword0 + wi) << 5;
            while (m) {
                int bit = __builtin_ctz(m);
                m &= m - 1;
                unsigned ppix = pbase + (unsigned)bit;
                int hh = (int)((ppix >> 11) & 2047u);
                int ww = (int)(ppix & 2047u);
                if (off < (unsigned)MAX_PEAKS) {
                    out[off] = hh;
                    out[MAX_PEAKS + off] = ww;
                }
                ++off;
            }
        }
    } else {
        unsigned total = base[1024];
        if (total > (unsigned)MAX_PEAKS) total = MAX_PEAKS;
        unsigned tail = (unsigned)MAX_PEAKS - total;
        unsigned fb = (unsigned)(b - 1024);
        unsigned per = (tail + NFILL - 1) / NFILL;
        unsigned s = total + fb * per;
        unsigned e = s + per;
        if (s > (unsigned)MAX_PEAKS) s = MAX_PEAKS;
        if (e > (unsigned)MAX_PEAKS) e = MAX_PEAKS;
        unsigned a = (s + 3u) & ~3u;
        if (a > e) a = e;
        unsigned e4 = e & ~3u;
        if (e4 < a) e4 = a;
        // head scalars [s, a)  (<=3 elems)
        if ((unsigned)t < a - s) {
            out[s + t] = -1;
            out[MAX_PEAKS + s + t] = -1;
        }
        // aligned body [a, e4) as int4 (MAX_PEAKS % 4 == 0 -> both planes aligned)
        const int4 m4 = make_int4(-1, -1, -1, -1);
        for (unsigned k = a / 4 + t; k < e4 / 4; k += 256) {
            ((int4*)out)[k] = m4;
            ((int4*)(out + MAX_PEAKS))[k] = m4;
        }
        // tail scalars [e4, e)  (<=3 elems)
        if ((unsigned)t < e - e4) {
            out[e4 + t] = -1;
            out[MAX_PEAKS + e4 + t] = -1;
        }
    }
}

extern "C" void kernel_launch(void* const* d_in, const int* in_sizes, int n_in,
                              void* d_out, int out_size, void* d_ws, size_t ws_size,
                              hipStream_t stream) {
    const float* scores = (const float*)d_in[0];
    int* out = (int*)d_out;
    unsigned* words = (unsigned*)d_ws;            // 1,048,576 words (4 MB)
    unsigned* bsum2 = words + NWORDS;             // 8192 per-(chunk,strip) sums
    unsigned* base = bsum2 + 8192;                // 1025 (incl. total)

    nms_mask<<<1024, 256, 0, stream>>>(scores, words, bsum2);
    nms_scan<<<1, 256, 0, stream>>>(bsum2, base);
    nms_compact<<<1024 + NFILL, 256, 0, stream>>>(words, base, out);
}